// Round 8
// baseline (211.218 us; speedup 1.0000x reference)
//
#include <hip/hip_runtime.h>
#include <cstdint>
#include <cstddef>

#define DEVI __device__ __forceinline__

typedef __bf16 bf16_t;
typedef __bf16 bf16x4 __attribute__((ext_vector_type(4)));
typedef __bf16 bf16x8 __attribute__((ext_vector_type(8)));
typedef float  f32x4  __attribute__((ext_vector_type(4)));
typedef float  f32x16 __attribute__((ext_vector_type(16)));
typedef unsigned short u16x4 __attribute__((ext_vector_type(4)));
typedef unsigned int   u32x4 __attribute__((ext_vector_type(4)));

static constexpr int Bz = 2, S = 2048, E = 1024, H = 16, Dh = 64;
static constexpr int M  = Bz * S;   // 4096 tokens
static constexpr int N  = H * Dh;   // 1024
static constexpr int Kd = E;        // 1024

DEVI unsigned short f2bf(float f) {
  unsigned u = __builtin_bit_cast(unsigned, f);
  return (unsigned short)((u + 0x7fffu + ((u >> 16) & 1u)) >> 16);
}

DEVI void async_copy16(void* lds, const void* g) {
  __builtin_amdgcn_global_load_lds((__attribute__((address_space(1))) void*)(g),
                                   (__attribute__((address_space(3))) void*)(lds), 16, 0, 0);
}

DEVI void block_sync() { asm volatile("s_barrier" ::: "memory"); }
#define LGKM0()  asm volatile("s_waitcnt lgkmcnt(0)" ::: "memory")

// pack two f32 -> dword of two bf16 (RNE)
DEVI unsigned cvtpk(float lo, float hi) {
  unsigned r;
  asm("v_cvt_pk_bf16_f32 %0, %1, %2" : "=v"(r) : "v"(lo), "v"(hi));
  return r;
}
// swap x's lanes 32-63 with y's lanes 0-31
DEVI void swap32(unsigned& x, unsigned& y) {
  asm("v_permlane32_swap_b32 %0, %1" : "+v"(x), "+v"(y));
}

// ---------------- fused prep: convx | wtrans | rope table ----------------
__global__ void prep_kernel(const float* __restrict__ x, bf16_t* __restrict__ xb,
                            const float* __restrict__ Wq, const float* __restrict__ Wk,
                            const float* __restrict__ Wv, const float* __restrict__ Wo,
                            bf16_t* __restrict__ WtBase,
                            float* __restrict__ ropeC, float* __restrict__ ropeS) {
  __shared__ unsigned short tile[64][68];
  const int blk = blockIdx.x, tid = threadIdx.x;
  if (blk < 4096) {
    // x fp32 -> bf16
    int i = blk * 256 + tid;
    float4 v = ((const float4*)x)[i];
    u16x4 o = { f2bf(v.x), f2bf(v.y), f2bf(v.z), f2bf(v.w) };
    ((u16x4*)xb)[i] = o;
  } else if (blk < 5120) {
    // weight fp32 [K][N] -> bf16 [N][K]
    const int i = blk - 4096;
    const int z = i >> 8, rest = i & 255;
    const int n0 = (rest & 15) * 64, k0 = (rest >> 4) * 64;
    const float* W = (z == 0) ? Wq : (z == 1) ? Wk : (z == 2) ? Wv : Wo;
    unsigned short* T = (unsigned short*)(WtBase + (size_t)z * Kd * N);
    for (int e = tid; e < 1024; e += 256) {
      int r = e >> 4, c4 = (e & 15) * 4;
      float4 v = *(const float4*)(W + (size_t)(k0 + r) * N + n0 + c4);
      u16x4 o = { f2bf(v.x), f2bf(v.y), f2bf(v.z), f2bf(v.w) };
      *(u16x4*)&tile[r][c4] = o;
    }
    __syncthreads();
    for (int e = tid; e < 1024; e += 256) {
      int r = e >> 4, c4 = (e & 15) * 4;
      u16x4 o = { tile[c4][r], tile[c4 + 1][r], tile[c4 + 2][r], tile[c4 + 3][r] };
      *(u16x4*)&T[(size_t)(n0 + r) * Kd + k0 + c4] = o;
    }
  } else {
    int i = (blk - 5120) * 256 + tid;            // 65536 = 2048*32
    int pos = i >> 5, j = i & 31;
    float inv = exp2f(-(float)j * 0.41524101186092029f);   // log2(10000)/32
    float ang = (float)pos * inv;
    ropeC[i] = cosf(ang);
    ropeS[i] = sinf(ang);
  }
}

// bf16 [BH][S][D] -> tile-blocked V^T: [BH][S/32][D][32]  (dense 4KB per 32-key tile)
__global__ void vtrans_kernel(const bf16_t* __restrict__ V, bf16_t* __restrict__ Vt) {
  __shared__ unsigned short tile[64][68];
  const int bh = blockIdx.y;
  const int s0 = blockIdx.x * 64;
  const unsigned short* Vp = (const unsigned short*)V + (size_t)bh * S * Dh;
  unsigned short* Tp = (unsigned short*)Vt + (size_t)bh * S * Dh;
  const int tid = threadIdx.x;
  for (int e = tid; e < 1024; e += 256) {
    int r = e >> 4, c4 = (e & 15) * 4;
    u16x4 v = *(const u16x4*)(Vp + (size_t)(s0 + r) * Dh + c4);
    *(u16x4*)&tile[r][c4] = v;
  }
  __syncthreads();
  for (int e = tid; e < 1024; e += 256) {
    int d = e >> 4, s4 = (e & 15) * 4;
    int t = (s0 + s4) >> 5, ks = (s0 + s4) & 31;      // s4 is 4-aligned, no 32-crossing
    u16x4 o = { tile[s4][d], tile[s4 + 1][d], tile[s4 + 2][d], tile[s4 + 3][d] };
    *(u16x4*)&Tp[((size_t)t * Dh + d) * 32 + ks] = o;
  }
}

// ---------------- GEMM core (128x128 tile, BK=32, global_load_lds) ----------------

DEVI void gemm_mainloop(const bf16_t* __restrict__ A, const bf16_t* __restrict__ Bt,
                        bf16_t* sA, bf16_t* sB, int m0, int n0, f32x4 (&acc)[4][4]) {
  const int tid  = threadIdx.x;
  const int lane = tid & 63;
  const int wid  = tid >> 6;
  const int l16  = lane & 15;
  const int quad = lane >> 4;
  const int wm = (wid >> 1) * 64;
  const int wn = (wid & 1) * 64;
  const int o0 = wid * 2048 + lane * 16;   // byte offset within 8KB tile
  const int o1 = o0 + 1024;
  const int r0 = o0 >> 6, c0 = o0 & 63;
  const int r1 = o1 >> 6, c1 = o1 & 63;
  const char* Ab = (const char*)A;
  const char* Bb = (const char*)Bt;
  char* sAc = (char*)sA;
  char* sBc = (char*)sB;

  for (int k0 = 0; k0 < Kd; k0 += 32) {
    __syncthreads();
    async_copy16(sAc + wid * 2048,        Ab + ((size_t)(m0 + r0) * Kd + k0) * 2 + c0);
    async_copy16(sAc + wid * 2048 + 1024, Ab + ((size_t)(m0 + r1) * Kd + k0) * 2 + c1);
    async_copy16(sBc + wid * 2048,        Bb + ((size_t)(n0 + r0) * Kd + k0) * 2 + c0);
    async_copy16(sBc + wid * 2048 + 1024, Bb + ((size_t)(n0 + r1) * Kd + k0) * 2 + c1);
    __syncthreads();
    bf16x8 af[4], bfv[4];
#pragma unroll
    for (int mi = 0; mi < 4; ++mi)
      af[mi] = *(const bf16x8*)(sA + (wm + mi * 16 + l16) * 32 + quad * 8);
#pragma unroll
    for (int ni = 0; ni < 4; ++ni)
      bfv[ni] = *(const bf16x8*)(sB + (wn + ni * 16 + l16) * 32 + quad * 8);
#pragma unroll
    for (int mi = 0; mi < 4; ++mi)
#pragma unroll
      for (int ni = 0; ni < 4; ++ni)
        acc[mi][ni] = __builtin_amdgcn_mfma_f32_16x16x32_bf16(af[mi], bfv[ni], acc[mi][ni], 0, 0, 0);
  }
}

// z = 0:Q(RoPE+scale) 1:K(RoPE) 2:V ; out layout [B,H,S,D] bf16
__global__ __launch_bounds__(256, 3) void gemm_qkv_kernel(
    const bf16_t* __restrict__ xb, const bf16_t* __restrict__ WtBase,
    const float* __restrict__ bq, const float* __restrict__ bk, const float* __restrict__ bv,
    bf16_t* __restrict__ outBase,
    const float* __restrict__ ropeC, const float* __restrict__ ropeS) {
  __shared__ bf16_t sA[4096], sB[4096];
  const int z = blockIdx.z;
  const bf16_t* Bt = WtBase + (size_t)z * Kd * N;
  const float* bias = (z == 0) ? bq : (z == 1) ? bk : bv;
  unsigned short* outp = (unsigned short*)(outBase + (size_t)z * M * N);
  const int n0 = blockIdx.x * 128, m0 = blockIdx.y * 128;
  f32x4 acc[4][4] = {};
  gemm_mainloop(xb, Bt, sA, sB, m0, n0, acc);

  const int tid = threadIdx.x, lane = tid & 63, wid = tid >> 6;
  const int l16 = lane & 15, quad = lane >> 4;
  const int wm = (wid >> 1) * 64, wn = (wid & 1) * 64;
  const int cbase = n0 + wn;          // 64-aligned -> one head per wave slab
  const int h = cbase >> 6;

  if (z < 2) {
    // Q gets 0.125 (=1/sqrt(D)) * log2(e) folded in so attention can use exp2
    const float qs = (z == 0) ? 0.18033688011112042f : 1.0f;
#pragma unroll
    for (int mi = 0; mi < 4; ++mi)
#pragma unroll
      for (int r = 0; r < 4; ++r) {
        int t = m0 + wm + mi * 16 + quad * 4 + r;
        int bb = t >> 11, s = t & (S - 1);
        size_t obase = ((size_t)(bb * H + h) * S + s) * Dh;
#pragma unroll
        for (int np = 0; np < 2; ++np) {
          int j = np * 16 + l16;                 // = d (low half), d-32 (high half)
          float cc = ropeC[s * 32 + j];
          float ss = ropeS[s * 32 + j];
          float xlo = acc[mi][np][r]     + bias[cbase + j];
          float xhi = acc[mi][np + 2][r] + bias[cbase + j + 32];
          outp[obase + j]      = f2bf((xlo * cc - xhi * ss) * qs);
          outp[obase + j + 32] = f2bf((xhi * cc + xlo * ss) * qs);
        }
      }
  } else {
#pragma unroll
    for (int mi = 0; mi < 4; ++mi)
#pragma unroll
      for (int r = 0; r < 4; ++r) {
        int t = m0 + wm + mi * 16 + quad * 4 + r;
        int bb = t >> 11, s = t & (S - 1);
        size_t obase = ((size_t)(bb * H + h) * S + s) * Dh;
#pragma unroll
        for (int ni = 0; ni < 4; ++ni) {
          int d = ni * 16 + l16;
          outp[obase + d] = f2bf(acc[mi][ni][r] + bias[cbase + d]);
        }
      }
  }
}

// output GEMM: 64(m) x 128(n) tiles -> 512 blocks (2/CU)
__global__ __launch_bounds__(256, 4) void gemm_o_kernel(
    const bf16_t* __restrict__ A, const bf16_t* __restrict__ Bt,
    const float* __restrict__ bias, float* __restrict__ out) {
  __shared__ bf16_t sA[2048], sB[4096];     // 4KB A (64x32), 8KB B (128x32)
  const int n0 = blockIdx.x * 128, m0 = blockIdx.y * 64;
  const int tid = threadIdx.x, lane = tid & 63, wid = tid >> 6;
  const int l16 = lane & 15, quad = lane >> 4;
  const int wm = (wid >> 1) * 32, wn = (wid & 1) * 64;
  const int rowoff = lane >> 2, col8 = (lane & 3) * 8;
  const char* Ab = (const char*)A;
  const char* Bb = (const char*)Bt;
  char* sAc = (char*)sA;
  char* sBc = (char*)sB;
  f32x4 acc[2][4] = {};

  for (int k0 = 0; k0 < Kd; k0 += 32) {
    __syncthreads();
    async_copy16(sAc + wid * 1024,
                 Ab + ((size_t)(m0 + wid * 16 + rowoff) * Kd + k0 + col8) * 2);
    async_copy16(sBc + (wid * 2) * 1024,
                 Bb + ((size_t)(n0 + wid * 32 + rowoff) * Kd + k0 + col8) * 2);
    async_copy16(sBc + (wid * 2 + 1) * 1024,
                 Bb + ((size_t)(n0 + wid * 32 + 16 + rowoff) * Kd + k0 + col8) * 2);
    __syncthreads();
    bf16x8 af[2], bfv[4];
#pragma unroll
    for (int mi = 0; mi < 2; ++mi)
      af[mi] = *(const bf16x8*)(sA + (wm + mi * 16 + l16) * 32 + quad * 8);
#pragma unroll
    for (int ni = 0; ni < 4; ++ni)
      bfv[ni] = *(const bf16x8*)(sB + (wn + ni * 16 + l16) * 32 + quad * 8);
#pragma unroll
    for (int mi = 0; mi < 2; ++mi)
#pragma unroll
      for (int ni = 0; ni < 4; ++ni)
        acc[mi][ni] = __builtin_amdgcn_mfma_f32_16x16x32_bf16(af[mi], bfv[ni], acc[mi][ni], 0, 0, 0);
  }
#pragma unroll
  for (int mi = 0; mi < 2; ++mi)
#pragma unroll
    for (int r = 0; r < 4; ++r) {
      int t = m0 + wm + mi * 16 + quad * 4 + r;
#pragma unroll
      for (int ni = 0; ni < 4; ++ni) {
        int c = n0 + wn + ni * 16 + l16;
        out[(size_t)t * N + c] = acc[mi][ni][r] + bias[c];
      }
    }
}

// ------- flash attention: 32x32 MFMA, 128-row q-tiles, 2-way split-K,
//         BARRIER-FREE main loop with direct-from-L2 K/V register loads -------
// 512 blocks x 512 threads (8 waves = 4 q-position waves x 2 split-K groups).
// Block handles q-tile j (128 rows; wave w4 owns rows j*128 + w4*32 ..+32);
// group g covers keys [g*(j+1)*64, (g+1)*(j+1)*64) as 2(j+1) 32-key subtiles.
// K/V is L2-resident (per-XCD footprint ~4MB; bh in low 5 bits of blockIdx ->
// all 16 blocks of a bh land on one XCD), so LDS staging is pure overhead:
// every prior round paid ~3.3k cyc per barrier-delimited phase for ~1k cyc of
// work. Here each wave loads its K/V fragments straight to VGPRs (8 dwordx4
// per subtile, addresses = the r7-verified staging offsets) and free-runs:
// NO main-loop barriers, no global_load_lds, no vmcnt choreography. 4 waves/
// SIMD + unroll-2 ILP hide L2 latency. One barrier before the 2-way combine.
// Fixed-m softmax (scale*log2e folded into Q) -> split-K combine additive.
// QK^T swapped (K as A-op) -> P in D-layout -> cvt_pk + permlane32 to PV B-op
// in-register. V via tile-blocked dense V^T [S/32][D][32].
template <bool MASKED>
DEVI void attn32_tile(const bf16_t* __restrict__ Qp, const char* __restrict__ Kg,
                      const char* __restrict__ Vg, const int* __restrict__ mp,
                      unsigned short* __restrict__ cp, char* lds,
                      int b, int bh, int j) {
  const int tid = threadIdx.x, lane = tid & 63, wid = tid >> 6;
  const int grp = wid >> 2, w4 = wid & 3;
  const int l32 = lane & 31, hi = lane >> 5;

  const int qw = j * 128 + w4 * 32;        // wave's first q row
  const int qg = qw + l32;                 // this lane's q (as D-col)
  const int nSub = 2 * (j + 1);            // 32-key subtiles for my group
  const int gk0 = grp * (j + 1) * 64;      // group's first key

  // Q fragments (B-operand): B[k = hi*8+jj][n = q = l32], d-chunk c
  bf16x8 qf[4];
#pragma unroll
  for (int c = 0; c < 4; ++c)
    qf[c] = *(const bf16x8*)(Qp + (size_t)(qw + l32) * Dh + c * 16 + hi * 8);

  // per-lane base offsets (r7-verified fragment<->global mapping)
  const char* kp0 = Kg + (size_t)l32 * 128 + hi * 16;          // + kb*128 + c*32
  const char* vp0 = Vg + (size_t)l32 * 64 + hi * 16;           // + (kb>>5)*4096 + (v>>1)*2048 + (v&1)*32

  f32x16 cacc0 = {}, cacc1 = {};
  float lsum = 0.f;

#pragma unroll 2
  for (int kt = 0; kt < nSub; ++kt) {
    const int kb = gk0 + kt * 32;
    // direct register loads from L2 (no LDS, no barriers)
    const char* kp = kp0 + (size_t)kb * 128;
    const char* vp = vp0 + (size_t)(kb >> 5) * 4096;
    bf16x8 kf0 = *(const bf16x8*)(kp);
    bf16x8 kf1 = *(const bf16x8*)(kp + 32);
    bf16x8 kf2 = *(const bf16x8*)(kp + 64);
    bf16x8 kf3 = *(const bf16x8*)(kp + 96);
    bf16x8 v00 = *(const bf16x8*)(vp);
    bf16x8 v01 = *(const bf16x8*)(vp + 32);
    bf16x8 v10 = *(const bf16x8*)(vp + 2048);
    bf16x8 v11 = *(const bf16x8*)(vp + 2048 + 32);
    unsigned long long dm = 0;
    if (MASKED) {
      int mk = mp[kb + l32];
      dm = __ballot(mk == 0);
    }

    // S^T(32 keys x 32 q) = K . Q^T over d (4 chunks of 16)
    f32x16 st = {};
    __builtin_amdgcn_s_setprio(1);
    st = __builtin_amdgcn_mfma_f32_32x32x16_bf16(kf0, qf[0], st, 0, 0, 0);
    st = __builtin_amdgcn_mfma_f32_32x32x16_bf16(kf1, qf[1], st, 0, 0, 0);
    st = __builtin_amdgcn_mfma_f32_32x32x16_bf16(kf2, qf[2], st, 0, 0, 0);
    st = __builtin_amdgcn_mfma_f32_32x32x16_bf16(kf3, qf[3], st, 0, 0, 0);
    __builtin_amdgcn_s_setprio(0);

    // D layout: col = q = l32, key-in-32 = (r&3) + 8*(r>>2) + 4*hi
    if (MASKED && dm) {
#pragma unroll
      for (int r = 0; r < 16; ++r)
        if ((dm >> ((r & 3) + 8 * (r >> 2) + 4 * hi)) & 1ull) st[r] = -1e30f;
    }
    if (kb + 31 > qw) {               // causal mask touches this subtile
      const int kbase = kb + 4 * hi - qg;
#pragma unroll
      for (int r = 0; r < 16; ++r)
        if (kbase + (r & 3) + 8 * (r >> 2) > 0) st[r] = -1e30f;
    }
    // p = exp2(s) (fixed m); pack pairs to bf16 dwords
    unsigned P0[4], P1[4];
#pragma unroll
    for (int m = 0; m < 4; ++m) {
      float p0 = exp2f(st[4 * m + 0]), p1 = exp2f(st[4 * m + 1]);
      float p2 = exp2f(st[4 * m + 2]), p3 = exp2f(st[4 * m + 3]);
      lsum += (p0 + p1) + (p2 + p3);
      P0[m] = cvtpk(p0, p1);
      P1[m] = cvtpk(p2, p3);
    }
    // permlane32_swap -> PV B-operand frags (keys [0,16) and [16,32))
    swap32(P0[0], P0[1]); swap32(P1[0], P1[1]);
    swap32(P0[2], P0[3]); swap32(P1[2], P1[3]);
    u32x4 t0 = { P0[0], P1[0], P0[1], P1[1] };
    u32x4 t1 = { P0[2], P1[2], P0[3], P1[3] };
    const bf16x8 f0 = __builtin_bit_cast(bf16x8, t0);
    const bf16x8 f1 = __builtin_bit_cast(bf16x8, t1);
    // ctx^T += V^T . P^T
    __builtin_amdgcn_s_setprio(1);
    cacc0 = __builtin_amdgcn_mfma_f32_32x32x16_bf16(v00, f0, cacc0, 0, 0, 0);
    cacc0 = __builtin_amdgcn_mfma_f32_32x32x16_bf16(v01, f1, cacc0, 0, 0, 0);
    cacc1 = __builtin_amdgcn_mfma_f32_32x32x16_bf16(v10, f0, cacc1, 0, 0, 0);
    cacc1 = __builtin_amdgcn_mfma_f32_32x32x16_bf16(v11, f1, cacc1, 0, 0, 0);
    __builtin_amdgcn_s_setprio(0);
  }

  // ---- 2-way split-K combine: grp1 stores rotated partials, grp0 reduces ----
  // region per w4: f32 [q 32][d 64] (8KB) at reg + w4*2048; rotation
  // (d + 4q)&63 -> bank-spread f32x4. lsum at float ofs 8192 + w4*32 + l32.
  lsum += __shfl_xor(lsum, 32);       // fold key-halves: all lanes = full lsum(q)
  float* reg = (float*)lds;
  if (grp == 1) {
    float* rb = reg + w4 * 2048 + l32 * 64;
#pragma unroll
    for (int m = 0; m < 4; ++m) {
      f32x4 v = { cacc0[4 * m], cacc0[4 * m + 1], cacc0[4 * m + 2], cacc0[4 * m + 3] };
      *(f32x4*)(rb + ((8 * m + 4 * hi + 4 * l32) & 63)) = v;
    }
#pragma unroll
    for (int m = 0; m < 4; ++m) {
      f32x4 v = { cacc1[4 * m], cacc1[4 * m + 1], cacc1[4 * m + 2], cacc1[4 * m + 3] };
      *(f32x4*)(rb + ((32 + 8 * m + 4 * hi + 4 * l32) & 63)) = v;
    }
    reg[8192 + w4 * 32 + l32] = lsum;
  }
  LGKM0();
  block_sync();
  if (grp == 0) {
    const float* rb = reg + w4 * 2048 + l32 * 64;
#pragma unroll
    for (int m = 0; m < 4; ++m) {
      f32x4 v = *(const f32x4*)(rb + ((8 * m + 4 * hi + 4 * l32) & 63));
      cacc0[4 * m] += v[0]; cacc0[4 * m + 1] += v[1];
      cacc0[4 * m + 2] += v[2]; cacc0[4 * m + 3] += v[3];
    }
#pragma unroll
    for (int m = 0; m < 4; ++m) {
      f32x4 v = *(const f32x4*)(rb + ((32 + 8 * m + 4 * hi + 4 * l32) & 63));
      cacc1[4 * m] += v[0]; cacc1[4 * m + 1] += v[1];
      cacc1[4 * m + 2] += v[2]; cacc1[4 * m + 3] += v[3];
    }
    const float inv = 1.0f / (lsum + reg[8192 + w4 * 32 + l32]);
    const size_t base = ((size_t)(b * S + qw + l32)) * N + (size_t)(bh & 15) * Dh;
#pragma unroll
    for (int m = 0; m < 4; ++m) {
      const int d0 = m * 8 + 4 * hi;   // d = (r&3) + 8m + 4hi
      u16x4 o0 = { f2bf(cacc0[4 * m + 0] * inv), f2bf(cacc0[4 * m + 1] * inv),
                   f2bf(cacc0[4 * m + 2] * inv), f2bf(cacc0[4 * m + 3] * inv) };
      *(u16x4*)&cp[base + d0] = o0;
      u16x4 o1 = { f2bf(cacc1[4 * m + 0] * inv), f2bf(cacc1[4 * m + 1] * inv),
                   f2bf(cacc1[4 * m + 2] * inv), f2bf(cacc1[4 * m + 3] * inv) };
      *(u16x4*)&cp[base + 32 + d0] = o1;
    }
  }
}

__global__ __launch_bounds__(512, 4) void attn_kernel(
    const bf16_t* __restrict__ Q, const bf16_t* __restrict__ Kb,
    const bf16_t* __restrict__ Vt, const int* __restrict__ mask,
    bf16_t* __restrict__ ctx) {
  __shared__ float ldsbuf[8448];               // 33 KB (combine only)

  const int idx = blockIdx.x;                  // 512 blocks
  const int t   = idx >> 5;
  const int j   = (t < 8) ? (15 - t) : (t - 8);  // pairs {c,c+256} sum to 17 slots
  const int bh  = idx & 31;                      // low bits -> XCD locality
  const int b   = bh >> 4;
  const int lane = threadIdx.x & 63;

  const bf16_t* Qp = Q + (size_t)bh * S * Dh;
  const char*   Kg = (const char*)(Kb + (size_t)bh * S * Dh);
  const char*   Vg = (const char*)(Vt + (size_t)bh * S * Dh);   // tile-blocked V^T
  const int*    mp = mask + b * S;

  // one pass over the mask row: all-alive -> fast path (no in-loop mask vmem)
  int dead = 0;
  const int4* mp4 = (const int4*)mp;
  for (int c = lane; c < S / 4; c += 64) {
    int4 m = mp4[c];
    dead |= (m.x == 0) | (m.y == 0) | (m.z == 0) | (m.w == 0);
  }
  const bool anydead = __ballot(dead != 0) != 0ull;

  unsigned short* cp = (unsigned short*)ctx;
  char* lds = (char*)ldsbuf;
  if (!anydead)
    attn32_tile<false>(Qp, Kg, Vg, mp, cp, lds, b, bh, j);
  else
    attn32_tile<true>(Qp, Kg, Vg, mp, cp, lds, b, bh, j);
}

// ---------------- launcher ----------------

extern "C" void kernel_launch(void* const* d_in, const int* in_sizes, int n_in,
                              void* d_out, int out_size, void* d_ws, size_t ws_size,
                              hipStream_t stream) {
  const float* x  = (const float*)d_in[0];
  const int*  msk = (const int*)d_in[1];
  const float* Wq = (const float*)d_in[2];
  const float* bq = (const float*)d_in[3];
  const float* Wk = (const float*)d_in[4];
  const float* bk = (const float*)d_in[5];
  const float* Wv = (const float*)d_in[6];
  const float* bv = (const float*)d_in[7];
  const float* Wo = (const float*)d_in[8];
  const float* bo = (const float*)d_in[9];
  float* out = (float*)d_out;
  (void)in_sizes; (void)n_in; (void)out_size; (void)ws_size;

  char* ws = (char*)d_ws;
  bf16_t* xb   = (bf16_t*)(ws);                      // 8 MB  [4096][1024]
  bf16_t* WT   = (bf16_t*)(ws + (8u  << 20));        // 8 MB  4 x [1024][1024] (N-major)
  bf16_t* qkv  = (bf16_t*)(ws + (16u << 20));        // 24 MB Q,K,V each [B,H,S,D]
  bf16_t* Qb   = qkv;
  bf16_t* Kbuf = qkv + (size_t)1 * M * N;
  bf16_t* Vb   = qkv + (size_t)2 * M * N;
  bf16_t* Vt   = xb;                                  // alias: xb dead after QKV GEMM
  bf16_t* ctx  = Vb;                                  // alias: V[B,H,S,D] dead after vtrans
  float* ropeC = (float*)(ws + (40u << 20));          // 256 KB
  float* ropeS = ropeC + (size_t)S * 32;              // 256 KB

  prep_kernel<<<5376, 256, 0, stream>>>(x, xb, Wq, Wk, Wv, Wo, WT, ropeC, ropeS);
  gemm_qkv_kernel<<<dim3(8, 32, 3), 256, 0, stream>>>(xb, WT, bq, bk, bv, qkv, ropeC, ropeS);
  vtrans_kernel<<<dim3(32, 32), 256, 0, stream>>>(Vb, Vt);
  attn_kernel<<<512, 512, 0, stream>>>(Qb, Kbuf, Vt, msk, ctx);
  gemm_o_kernel<<<dim3(8, 64), 256, 0, stream>>>(ctx, WT + (size_t)3 * Kd * N, bo, out);
}